// Round 2
// baseline (631.614 us; speedup 1.0000x reference)
//
#include <hip/hip_runtime.h>
#include <hip/hip_bf16.h>
#include <math.h>

#define NTOK 8192
#define HD 1024
#define ID 4096
#define NE 8
#define MAXTILES 72

typedef __attribute__((ext_vector_type(8))) short short8;
typedef __attribute__((ext_vector_type(4))) float floatx4;

__device__ __forceinline__ unsigned short f2bf(float f) {
  unsigned int u = __float_as_uint(f);
  return (unsigned short)((u + 0x7fffu + ((u >> 16) & 1u)) >> 16);
}

__device__ __forceinline__ void async_ld16(const void* g, void* l) {
  __builtin_amdgcn_global_load_lds(
      (const __attribute__((address_space(1))) unsigned int*)g,
      (__attribute__((address_space(3))) unsigned int*)l,
      16, 0, 0);
}

// ---------------- small kernels ----------------

__global__ void zero_counts_kernel(int* __restrict__ cnts) {
  if (threadIdx.x < 16) cnts[threadIdx.x] = 0;  // counts[8] + cursors[8]
}

// src: batch of [R][C] fp32, dst: batch of [C][R] bf16
__global__ void transpose_cast_kernel(const float* __restrict__ src,
                                      unsigned short* __restrict__ dst, int R, int C) {
  size_t bo = (size_t)blockIdx.z * R * C;
  src += bo; dst += bo;
  __shared__ float t[32][33];
  int c0 = blockIdx.x * 32, r0 = blockIdx.y * 32;
  int tx = threadIdx.x & 31, ty = threadIdx.x >> 5;
#pragma unroll
  for (int q = 0; q < 4; q++) {
    int r = ty + q * 8;
    t[r][tx] = src[(size_t)(r0 + r) * C + c0 + tx];
  }
  __syncthreads();
#pragma unroll
  for (int q = 0; q < 4; q++) {
    int cc = ty + q * 8;
    dst[(size_t)(c0 + cc) * R + r0 + tx] = f2bf(t[tx][cc]);
  }
}

// fp64-accumulated router logits + argmax; also emits xb = bf16(x) (fused cast)
__global__ void router_kernel(const float* __restrict__ x, const float* __restrict__ wr,
                              int* __restrict__ eidx, int* __restrict__ counts,
                              unsigned short* __restrict__ xb) {
  int wave = threadIdx.x >> 6, lane = threadIdx.x & 63;
  int n = blockIdx.x * 4 + wave;
  const float* xr = x + (size_t)n * HD;
  unsigned short* xbr = xb + (size_t)n * HD;
  double acc[NE];
#pragma unroll
  for (int e = 0; e < NE; e++) acc[e] = 0.0;
#pragma unroll
  for (int v = 0; v < 4; v++) {
    int h = (lane + v * 64) * 4;
    float4 xv = *(const float4*)(xr + h);
    ushort4 o;
    o.x = f2bf(xv.x); o.y = f2bf(xv.y); o.z = f2bf(xv.z); o.w = f2bf(xv.w);
    *(ushort4*)(xbr + h) = o;
#pragma unroll
    for (int e = 0; e < NE; e++) {
      float4 wv = *(const float4*)(wr + e * HD + h);
      acc[e] += (double)xv.x * wv.x + (double)xv.y * wv.y +
                (double)xv.z * wv.z + (double)xv.w * wv.w;
    }
  }
#pragma unroll
  for (int m = 32; m >= 1; m >>= 1) {
#pragma unroll
    for (int e = 0; e < NE; e++) acc[e] += __shfl_xor(acc[e], m, 64);
  }
  if (lane == 0) {
    int best = 0; double bv = acc[0];
#pragma unroll
    for (int e = 1; e < NE; e++) if (acc[e] > bv) { bv = acc[e]; best = e; }
    eidx[n] = best;
    atomicAdd(&counts[best], 1);
  }
}

// prefix-scan + M-tile table (<=71 tiles since sum(counts)=8192)
__global__ void scan_tiles_kernel(const int* __restrict__ counts, int* __restrict__ offs,
                                  int* __restrict__ ntiles, int* __restrict__ tile_e,
                                  int* __restrict__ tile_base, int* __restrict__ tile_len) {
  if (threadIdx.x == 0) {
    int s = 0, t = 0;
    for (int e = 0; e < NE; e++) {
      offs[e] = s;
      int c = counts[e];
      for (int b = 0; b < c; b += 128) {
        tile_e[t] = e;
        tile_base[t] = s + b;
        tile_len[t] = (c - b < 128) ? (c - b) : 128;
        t++;
      }
      s += c;
    }
    offs[NE] = s;
    *ntiles = t;
  }
}

__global__ void scatter_kernel(const int* __restrict__ eidx, const int* __restrict__ offs,
                               int* __restrict__ cursors, int* __restrict__ perm) {
  int n = blockIdx.x * 256 + threadIdx.x;
  int e = eidx[n];
  int pos = offs[e] + atomicAdd(&cursors[e], 1);
  perm[pos] = n;
}

// ---------------- GEMM kernels ----------------
// 128x128 tile, BK=64, 4 waves (2x2), 4x4 MFMA frags/wave, 16x16x32 bf16.
// LDS layout: [row][64] bf16, 16B chunks XOR-swizzled by (row&7) so both
// global_load_lds staging (lane*16 contiguous) and ds_read_b128 frag reads
// are conflict-free (SQ_LDS_BANK_CONFLICT==0 measured in R1).

__global__ __launch_bounds__(256, 2) void ffn1_kernel(
    const unsigned short* __restrict__ xb, const unsigned short* __restrict__ w1t,
    const float* __restrict__ b1, const int* __restrict__ perm,
    const int* __restrict__ ntiles, const int* __restrict__ tile_e,
    const int* __restrict__ tile_base, const int* __restrict__ tile_len,
    unsigned short* __restrict__ interb) {
  int t = blockIdx.y;
  if (t >= *ntiles) return;
  int e = tile_e[t], base = tile_base[t], len = tile_len[t];
  int nb = blockIdx.x * 128;

  __shared__ unsigned short lA[128 * 64];
  __shared__ unsigned short lB[128 * 64];

  int tid = threadIdx.x;
  int wave = tid >> 6, lane = tid & 63;
  int lr = lane >> 3;              // row-within-8-row-chunk
  int chunk = (lane & 7) ^ lr;     // swizzled 16B chunk selector

  const unsigned short* gA[4];
  const unsigned short* gB[4];
#pragma unroll
  for (int q = 0; q < 4; q++) {
    int c = wave * 4 + q;
    int tr = c * 8 + lr;
    int token = perm[base + (tr < len ? tr : len - 1)];  // clamp tail (stores masked)
    gA[q] = xb + (size_t)token * HD + chunk * 8;
    int nr = nb + c * 8 + lr;
    gB[q] = w1t + ((size_t)e * ID + nr) * HD + chunk * 8;
  }

  floatx4 acc[4][4];
#pragma unroll
  for (int i = 0; i < 4; i++)
#pragma unroll
    for (int j = 0; j < 4; j++) acc[i][j] = (floatx4){0.f, 0.f, 0.f, 0.f};

  int wm = (wave >> 1) * 64, wn = (wave & 1) * 64;
  int c15 = lane & 15, q4 = lane >> 4;

  for (int ko = 0; ko < HD / 64; ko++) {
#pragma unroll
    for (int q = 0; q < 4; q++) {
      int c = wave * 4 + q;
      async_ld16(gA[q] + ko * 64, &lA[c * 512]);
      async_ld16(gB[q] + ko * 64, &lB[c * 512]);
    }
    __syncthreads();
#pragma unroll
    for (int kk = 0; kk < 2; kk++) {
      short8 af[4], bfr[4];
#pragma unroll
      for (int i = 0; i < 4; i++) {
        int m = wm + i * 16 + c15;
        int sa = (kk * 4 + q4) ^ (m & 7);
        af[i] = *(const short8*)&lA[m * 64 + sa * 8];
        int n = wn + i * 16 + c15;
        int sb = (kk * 4 + q4) ^ (n & 7);
        bfr[i] = *(const short8*)&lB[n * 64 + sb * 8];
      }
#pragma unroll
      for (int i = 0; i < 4; i++)
#pragma unroll
        for (int j = 0; j < 4; j++)
          acc[i][j] = __builtin_amdgcn_mfma_f32_16x16x32_bf16(af[i], bfr[j], acc[i][j], 0, 0, 0);
    }
    __syncthreads();
  }

#pragma unroll
  for (int i = 0; i < 4; i++) {
#pragma unroll
    for (int r = 0; r < 4; r++) {
      int tr = wm + i * 16 + q4 * 4 + r;
      if (tr >= len) continue;
      int token = perm[base + tr];
#pragma unroll
      for (int j = 0; j < 4; j++) {
        int col = nb + wn + j * 16 + c15;
        float v = acc[i][j][r] + b1[e * ID + col];
        v = 0.5f * v * (1.0f + erff(v * 0.70710678118654752f));  // exact GELU
        interb[(size_t)token * ID + col] = f2bf(v);
      }
    }
  }
}

// split-K x2: z picks K-half [z*2048,(z+1)*2048); writes fp32 partial (no bias).
__global__ __launch_bounds__(256, 2) void ffn2_kernel(
    const unsigned short* __restrict__ interb, const unsigned short* __restrict__ wot,
    float* __restrict__ part) {
  int tm = blockIdx.y;
  int nb = blockIdx.x * 128;
  int kz = blockIdx.z;
  part += (size_t)kz * NTOK * HD;

  __shared__ unsigned short lA[128 * 64];
  __shared__ unsigned short lB[128 * 64];

  int tid = threadIdx.x;
  int wave = tid >> 6, lane = tid & 63;
  int lr = lane >> 3;
  int chunk = (lane & 7) ^ lr;

  const unsigned short* gA[4];
  const unsigned short* gB[4];
#pragma unroll
  for (int q = 0; q < 4; q++) {
    int c = wave * 4 + q;
    int row = tm * 128 + c * 8 + lr;
    gA[q] = interb + (size_t)row * ID + kz * 2048 + chunk * 8;
    int nr = nb + c * 8 + lr;
    gB[q] = wot + (size_t)nr * ID + kz * 2048 + chunk * 8;
  }

  floatx4 acc[4][4];
#pragma unroll
  for (int i = 0; i < 4; i++)
#pragma unroll
    for (int j = 0; j < 4; j++) acc[i][j] = (floatx4){0.f, 0.f, 0.f, 0.f};

  int wm = (wave >> 1) * 64, wn = (wave & 1) * 64;
  int c15 = lane & 15, q4 = lane >> 4;

  for (int ko = 0; ko < 2048 / 64; ko++) {
#pragma unroll
    for (int q = 0; q < 4; q++) {
      int c = wave * 4 + q;
      async_ld16(gA[q] + ko * 64, &lA[c * 512]);
      async_ld16(gB[q] + ko * 64, &lB[c * 512]);
    }
    __syncthreads();
#pragma unroll
    for (int kk = 0; kk < 2; kk++) {
      short8 af[4], bfr[4];
#pragma unroll
      for (int i = 0; i < 4; i++) {
        int m = wm + i * 16 + c15;
        int sa = (kk * 4 + q4) ^ (m & 7);
        af[i] = *(const short8*)&lA[m * 64 + sa * 8];
        int n = wn + i * 16 + c15;
        int sb = (kk * 4 + q4) ^ (n & 7);
        bfr[i] = *(const short8*)&lB[n * 64 + sb * 8];
      }
#pragma unroll
      for (int i = 0; i < 4; i++)
#pragma unroll
        for (int j = 0; j < 4; j++)
          acc[i][j] = __builtin_amdgcn_mfma_f32_16x16x32_bf16(af[i], bfr[j], acc[i][j], 0, 0, 0);
    }
    __syncthreads();
  }

#pragma unroll
  for (int i = 0; i < 4; i++) {
#pragma unroll
    for (int r = 0; r < 4; r++) {
      int row = tm * 128 + wm + i * 16 + q4 * 4 + r;
#pragma unroll
      for (int j = 0; j < 4; j++) {
        int col = nb + wn + j * 16 + c15;
        part[(size_t)row * HD + col] = acc[i][j][r];
      }
    }
  }
}

// fused: y = p0 + p1 + bo + x; LayerNorm(y) -> out
__global__ void ln_kernel(const float* __restrict__ p0, const float* __restrict__ x,
                          const float* __restrict__ bo, const float* __restrict__ gamma,
                          const float* __restrict__ beta, float* __restrict__ out) {
  int row = blockIdx.x, t = threadIdx.x;
  int lane = t & 63, wave = t >> 6;
  size_t ro = (size_t)row * HD + t * 4;
  float4 a = *(const float4*)(p0 + ro);
  float4 b = *(const float4*)(p0 + (size_t)NTOK * HD + ro);
  float4 xv = *(const float4*)(x + ro);
  float4 bv = *(const float4*)(bo + t * 4);
  float4 v;
  v.x = a.x + b.x + xv.x + bv.x;
  v.y = a.y + b.y + xv.y + bv.y;
  v.z = a.z + b.z + xv.z + bv.z;
  v.w = a.w + b.w + xv.w + bv.w;
  float s = v.x + v.y + v.z + v.w;
  float ss = v.x * v.x + v.y * v.y + v.z * v.z + v.w * v.w;
#pragma unroll
  for (int m = 32; m >= 1; m >>= 1) {
    s += __shfl_xor(s, m, 64);
    ss += __shfl_xor(ss, m, 64);
  }
  __shared__ float sred[4], ssred[4];
  if (lane == 0) { sred[wave] = s; ssred[wave] = ss; }
  __syncthreads();
  s = sred[0] + sred[1] + sred[2] + sred[3];
  ss = ssred[0] + ssred[1] + ssred[2] + ssred[3];
  float mu = s * (1.0f / HD);
  float var = ss * (1.0f / HD) - mu * mu;
  float rs = rsqrtf(var + 1e-12f);
  float4 g = *(const float4*)(gamma + t * 4);
  float4 be = *(const float4*)(beta + t * 4);
  float4 o;
  o.x = (v.x - mu) * rs * g.x + be.x;
  o.y = (v.y - mu) * rs * g.y + be.y;
  o.z = (v.z - mu) * rs * g.z + be.z;
  o.w = (v.w - mu) * rs * g.w + be.w;
  *(float4*)(out + ro) = o;
}

// ---------------- host launcher ----------------

extern "C" void kernel_launch(void* const* d_in, const int* in_sizes, int n_in,
                              void* d_out, int out_size, void* d_ws, size_t ws_size,
                              hipStream_t stream) {
  const float* x     = (const float*)d_in[0];
  const float* wr    = (const float*)d_in[1];
  const float* w1    = (const float*)d_in[2];
  const float* b1    = (const float*)d_in[3];
  const float* wo    = (const float*)d_in[4];
  const float* bo    = (const float*)d_in[5];
  const float* gamma = (const float*)d_in[6];
  const float* beta  = (const float*)d_in[7];
  float* out = (float*)d_out;

  char* p = (char*)d_ws;
  unsigned short* w1t = (unsigned short*)p; p += (size_t)NE * ID * HD * 2;   // 67 MB
  unsigned short* wot = (unsigned short*)p; p += (size_t)HD * ID * 2;        // 8.4 MB
  unsigned short* xb  = (unsigned short*)p; p += (size_t)NTOK * HD * 2;      // 16.8 MB
  unsigned short* interb = (unsigned short*)p; p += (size_t)NTOK * ID * 2;   // 67 MB
  int* eidx = (int*)p; p += (size_t)NTOK * 4;
  int* perm = (int*)p; p += (size_t)NTOK * 4;
  int* ints = (int*)p;
  int* counts    = ints;        // 8
  int* cursors   = ints + 8;    // 8
  int* offs      = ints + 16;   // 9
  int* ntiles    = ints + 25;   // 1
  int* tile_e    = ints + 32;   // 72
  int* tile_base = ints + 104;  // 72
  int* tile_len  = ints + 176;  // 72

  // partials alias w1t (dead after ffn1): 2 x 33.5 MB == 67 MB exactly
  float* part = (float*)w1t;

  zero_counts_kernel<<<1, 64, 0, stream>>>(counts);
  router_kernel<<<NTOK / 4, 256, 0, stream>>>(x, wr, eidx, counts, xb);
  transpose_cast_kernel<<<dim3(ID / 32, HD / 32, NE), 256, 0, stream>>>(w1, w1t, HD, ID);
  transpose_cast_kernel<<<dim3(HD / 32, ID / 32, 1), 256, 0, stream>>>(wo, wot, ID, HD);
  scan_tiles_kernel<<<1, 64, 0, stream>>>(counts, offs, ntiles, tile_e, tile_base, tile_len);
  scatter_kernel<<<NTOK / 256, 256, 0, stream>>>(eidx, offs, cursors, perm);
  ffn1_kernel<<<dim3(ID / 128, MAXTILES), 256, 0, stream>>>(
      xb, w1t, b1, perm, ntiles, tile_e, tile_base, tile_len, interb);
  ffn2_kernel<<<dim3(HD / 128, NTOK / 128, 2), 256, 0, stream>>>(interb, wot, part);
  ln_kernel<<<NTOK, 256, 0, stream>>>(part, x, bo, gamma, beta, out);
}

// Round 3
// 610.953 us; speedup vs baseline: 1.0338x; 1.0338x over previous
//
#include <hip/hip_runtime.h>
#include <hip/hip_bf16.h>
#include <math.h>

#define NTOK 8192
#define HD 1024
#define ID 4096
#define NE 8
#define MAXTILES 72

typedef __attribute__((ext_vector_type(8))) short short8;
typedef __attribute__((ext_vector_type(8))) unsigned short ushort8;
typedef __attribute__((ext_vector_type(4))) float floatx4;

__device__ __forceinline__ unsigned short f2bf(float f) {
  unsigned int u = __float_as_uint(f);
  return (unsigned short)((u + 0x7fffu + ((u >> 16) & 1u)) >> 16);
}

__device__ __forceinline__ void async_ld16(const void* g, void* l) {
  __builtin_amdgcn_global_load_lds(
      (const __attribute__((address_space(1))) unsigned int*)g,
      (__attribute__((address_space(3))) unsigned int*)l,
      16, 0, 0);
}

// ---------------- small kernels ----------------

__global__ void zero_counts_kernel(int* __restrict__ cnts) {
  if (threadIdx.x < 16) cnts[threadIdx.x] = 0;  // counts[8] + cursors[8]
}

// src: batch of [R][C] fp32, dst: batch of [C][R] bf16.
// 64x64 tile; float4 reads (16B/lane), ushort8 writes (16B/lane, 128B
// contiguous per 8-lane group). LDS padded to 65 -> <=2-way conflicts (free).
__global__ void transpose_cast_kernel(const float* __restrict__ src,
                                      unsigned short* __restrict__ dst, int R, int C) {
  size_t bo = (size_t)blockIdx.z * R * C;
  src += bo; dst += bo;
  __shared__ float t[64][65];
  int c0 = blockIdx.x * 64, r0 = blockIdx.y * 64;
  int tid = threadIdx.x;
  int rr = tid >> 4, c4 = (tid & 15) * 4;
#pragma unroll
  for (int q = 0; q < 4; q++) {
    int r = rr + q * 16;
    float4 v = *(const float4*)(src + (size_t)(r0 + r) * C + c0 + c4);
    t[r][c4] = v.x; t[r][c4 + 1] = v.y; t[r][c4 + 2] = v.z; t[r][c4 + 3] = v.w;
  }
  __syncthreads();
  int r8 = (tid & 7) * 8;
#pragma unroll
  for (int q = 0; q < 2; q++) {
    int cc = (tid >> 3) + q * 32;
    ushort8 o;
#pragma unroll
    for (int i = 0; i < 8; i++) o[i] = f2bf(t[r8 + i][cc]);
    *(ushort8*)(dst + (size_t)(c0 + cc) * R + r0 + r8) = o;
  }
}

// fp64-accumulated router logits + argmax; also emits xb = bf16(x) (fused cast)
__global__ void router_kernel(const float* __restrict__ x, const float* __restrict__ wr,
                              int* __restrict__ eidx, int* __restrict__ counts,
                              unsigned short* __restrict__ xb) {
  int wave = threadIdx.x >> 6, lane = threadIdx.x & 63;
  int n = blockIdx.x * 4 + wave;
  const float* xr = x + (size_t)n * HD;
  unsigned short* xbr = xb + (size_t)n * HD;
  double acc[NE];
#pragma unroll
  for (int e = 0; e < NE; e++) acc[e] = 0.0;
#pragma unroll
  for (int v = 0; v < 4; v++) {
    int h = (lane + v * 64) * 4;
    float4 xv = *(const float4*)(xr + h);
    ushort4 o;
    o.x = f2bf(xv.x); o.y = f2bf(xv.y); o.z = f2bf(xv.z); o.w = f2bf(xv.w);
    *(ushort4*)(xbr + h) = o;
#pragma unroll
    for (int e = 0; e < NE; e++) {
      float4 wv = *(const float4*)(wr + e * HD + h);
      acc[e] += (double)xv.x * wv.x + (double)xv.y * wv.y +
                (double)xv.z * wv.z + (double)xv.w * wv.w;
    }
  }
#pragma unroll
  for (int m = 32; m >= 1; m >>= 1) {
#pragma unroll
    for (int e = 0; e < NE; e++) acc[e] += __shfl_xor(acc[e], m, 64);
  }
  if (lane == 0) {
    int best = 0; double bv = acc[0];
#pragma unroll
    for (int e = 1; e < NE; e++) if (acc[e] > bv) { bv = acc[e]; best = e; }
    eidx[n] = best;
    atomicAdd(&counts[best], 1);
  }
}

// prefix-scan + M-tile table (<=71 tiles since sum(counts)=8192)
__global__ void scan_tiles_kernel(const int* __restrict__ counts, int* __restrict__ offs,
                                  int* __restrict__ ntiles, int* __restrict__ tile_e,
                                  int* __restrict__ tile_base, int* __restrict__ tile_len) {
  if (threadIdx.x == 0) {
    int s = 0, t = 0;
    for (int e = 0; e < NE; e++) {
      offs[e] = s;
      int c = counts[e];
      for (int b = 0; b < c; b += 128) {
        tile_e[t] = e;
        tile_base[t] = s + b;
        tile_len[t] = (c - b < 128) ? (c - b) : 128;
        t++;
      }
      s += c;
    }
    offs[NE] = s;
    *ntiles = t;
  }
}

__global__ void scatter_kernel(const int* __restrict__ eidx, const int* __restrict__ offs,
                               int* __restrict__ cursors, int* __restrict__ perm) {
  int n = blockIdx.x * 256 + threadIdx.x;
  int e = eidx[n];
  int pos = offs[e] + atomicAdd(&cursors[e], 1);
  perm[pos] = n;
}

// ---------------- GEMM kernels ----------------
// 128x128 tile, BK=64, 4 waves (2x2), 4x4 MFMA frags/wave, 16x16x32 bf16.
// LDS layout: [row][64] bf16, 16B chunks XOR-swizzled by (row&7) so both
// global_load_lds staging (lane*16 contiguous) and ds_read_b128 frag reads
// are conflict-free (SQ_LDS_BANK_CONFLICT==0 measured in R1/R2).

__global__ __launch_bounds__(256, 2) void ffn1_kernel(
    const unsigned short* __restrict__ xb, const unsigned short* __restrict__ w1t,
    const float* __restrict__ b1, const int* __restrict__ perm,
    const int* __restrict__ ntiles, const int* __restrict__ tile_e,
    const int* __restrict__ tile_base, const int* __restrict__ tile_len,
    unsigned short* __restrict__ interb) {
  int t = blockIdx.y;
  if (t >= *ntiles) return;
  int e = tile_e[t], base = tile_base[t], len = tile_len[t];
  int nb = blockIdx.x * 128;

  __shared__ unsigned short lA[128 * 64];
  __shared__ unsigned short lB[128 * 64];

  int tid = threadIdx.x;
  int wave = tid >> 6, lane = tid & 63;
  int lr = lane >> 3;              // row-within-8-row-chunk
  int chunk = (lane & 7) ^ lr;     // swizzled 16B chunk selector

  const unsigned short* gA[4];
  const unsigned short* gB[4];
#pragma unroll
  for (int q = 0; q < 4; q++) {
    int c = wave * 4 + q;
    int tr = c * 8 + lr;
    int token = perm[base + (tr < len ? tr : len - 1)];  // clamp tail (stores masked)
    gA[q] = xb + (size_t)token * HD + chunk * 8;
    int nr = nb + c * 8 + lr;
    gB[q] = w1t + ((size_t)e * ID + nr) * HD + chunk * 8;
  }

  floatx4 acc[4][4];
#pragma unroll
  for (int i = 0; i < 4; i++)
#pragma unroll
    for (int j = 0; j < 4; j++) acc[i][j] = (floatx4){0.f, 0.f, 0.f, 0.f};

  int wm = (wave >> 1) * 64, wn = (wave & 1) * 64;
  int c15 = lane & 15, q4 = lane >> 4;

  for (int ko = 0; ko < HD / 64; ko++) {
#pragma unroll
    for (int q = 0; q < 4; q++) {
      int c = wave * 4 + q;
      async_ld16(gA[q] + ko * 64, &lA[c * 512]);
      async_ld16(gB[q] + ko * 64, &lB[c * 512]);
    }
    __syncthreads();
#pragma unroll
    for (int kk = 0; kk < 2; kk++) {
      short8 af[4], bfr[4];
#pragma unroll
      for (int i = 0; i < 4; i++) {
        int m = wm + i * 16 + c15;
        int sa = (kk * 4 + q4) ^ (m & 7);
        af[i] = *(const short8*)&lA[m * 64 + sa * 8];
        int n = wn + i * 16 + c15;
        int sb = (kk * 4 + q4) ^ (n & 7);
        bfr[i] = *(const short8*)&lB[n * 64 + sb * 8];
      }
#pragma unroll
      for (int i = 0; i < 4; i++)
#pragma unroll
        for (int j = 0; j < 4; j++)
          acc[i][j] = __builtin_amdgcn_mfma_f32_16x16x32_bf16(af[i], bfr[j], acc[i][j], 0, 0, 0);
    }
    __syncthreads();
  }

#pragma unroll
  for (int i = 0; i < 4; i++) {
#pragma unroll
    for (int r = 0; r < 4; r++) {
      int tr = wm + i * 16 + q4 * 4 + r;
      if (tr >= len) continue;
      int token = perm[base + tr];
#pragma unroll
      for (int j = 0; j < 4; j++) {
        int col = nb + wn + j * 16 + c15;
        float v = acc[i][j][r] + b1[e * ID + col];
        v = 0.5f * v * (1.0f + erff(v * 0.70710678118654752f));  // exact GELU
        interb[(size_t)token * ID + col] = f2bf(v);
      }
    }
  }
}

// full-K ffn2, fused bias + residual; writes pre-LN y (fp32) to d_out.
__global__ __launch_bounds__(256, 2) void ffn2_kernel(
    const unsigned short* __restrict__ interb, const unsigned short* __restrict__ wot,
    const float* __restrict__ bo, const float* __restrict__ x, float* __restrict__ y) {
  int tm = blockIdx.y;
  int nb = blockIdx.x * 128;

  __shared__ unsigned short lA[128 * 64];
  __shared__ unsigned short lB[128 * 64];

  int tid = threadIdx.x;
  int wave = tid >> 6, lane = tid & 63;
  int lr = lane >> 3;
  int chunk = (lane & 7) ^ lr;

  const unsigned short* gA[4];
  const unsigned short* gB[4];
#pragma unroll
  for (int q = 0; q < 4; q++) {
    int c = wave * 4 + q;
    int row = tm * 128 + c * 8 + lr;
    gA[q] = interb + (size_t)row * ID + chunk * 8;
    int nr = nb + c * 8 + lr;
    gB[q] = wot + (size_t)nr * ID + chunk * 8;
  }

  floatx4 acc[4][4];
#pragma unroll
  for (int i = 0; i < 4; i++)
#pragma unroll
    for (int j = 0; j < 4; j++) acc[i][j] = (floatx4){0.f, 0.f, 0.f, 0.f};

  int wm = (wave >> 1) * 64, wn = (wave & 1) * 64;
  int c15 = lane & 15, q4 = lane >> 4;

  for (int ko = 0; ko < ID / 64; ko++) {
#pragma unroll
    for (int q = 0; q < 4; q++) {
      int c = wave * 4 + q;
      async_ld16(gA[q] + ko * 64, &lA[c * 512]);
      async_ld16(gB[q] + ko * 64, &lB[c * 512]);
    }
    __syncthreads();
#pragma unroll
    for (int kk = 0; kk < 2; kk++) {
      short8 af[4], bfr[4];
#pragma unroll
      for (int i = 0; i < 4; i++) {
        int m = wm + i * 16 + c15;
        int sa = (kk * 4 + q4) ^ (m & 7);
        af[i] = *(const short8*)&lA[m * 64 + sa * 8];
        int n = wn + i * 16 + c15;
        int sb = (kk * 4 + q4) ^ (n & 7);
        bfr[i] = *(const short8*)&lB[n * 64 + sb * 8];
      }
#pragma unroll
      for (int i = 0; i < 4; i++)
#pragma unroll
        for (int j = 0; j < 4; j++)
          acc[i][j] = __builtin_amdgcn_mfma_f32_16x16x32_bf16(af[i], bfr[j], acc[i][j], 0, 0, 0);
    }
    __syncthreads();
  }

#pragma unroll
  for (int i = 0; i < 4; i++) {
#pragma unroll
    for (int r = 0; r < 4; r++) {
      int row = tm * 128 + wm + i * 16 + q4 * 4 + r;
#pragma unroll
      for (int j = 0; j < 4; j++) {
        int col = nb + wn + j * 16 + c15;
        float v = acc[i][j][r] + bo[col] + x[(size_t)row * HD + col];
        y[(size_t)row * HD + col] = v;  // pre-LN y staged in d_out
      }
    }
  }
}

__global__ void ln_kernel(float* __restrict__ y, const float* __restrict__ gamma,
                          const float* __restrict__ beta) {
  int row = blockIdx.x, t = threadIdx.x;
  int lane = t & 63, wave = t >> 6;
  float* yr = y + (size_t)row * HD;
  float4 v = *(const float4*)(yr + t * 4);
  float s = v.x + v.y + v.z + v.w;
  float ss = v.x * v.x + v.y * v.y + v.z * v.z + v.w * v.w;
#pragma unroll
  for (int m = 32; m >= 1; m >>= 1) {
    s += __shfl_xor(s, m, 64);
    ss += __shfl_xor(ss, m, 64);
  }
  __shared__ float sred[4], ssred[4];
  if (lane == 0) { sred[wave] = s; ssred[wave] = ss; }
  __syncthreads();
  s = sred[0] + sred[1] + sred[2] + sred[3];
  ss = ssred[0] + ssred[1] + ssred[2] + ssred[3];
  float mu = s * (1.0f / HD);
  float var = ss * (1.0f / HD) - mu * mu;
  float rs = rsqrtf(var + 1e-12f);
  float4 g = *(const float4*)(gamma + t * 4);
  float4 b = *(const float4*)(beta + t * 4);
  float4 o;
  o.x = (v.x - mu) * rs * g.x + b.x;
  o.y = (v.y - mu) * rs * g.y + b.y;
  o.z = (v.z - mu) * rs * g.z + b.z;
  o.w = (v.w - mu) * rs * g.w + b.w;
  *(float4*)(yr + t * 4) = o;
}

// ---------------- host launcher ----------------

extern "C" void kernel_launch(void* const* d_in, const int* in_sizes, int n_in,
                              void* d_out, int out_size, void* d_ws, size_t ws_size,
                              hipStream_t stream) {
  const float* x     = (const float*)d_in[0];
  const float* wr    = (const float*)d_in[1];
  const float* w1    = (const float*)d_in[2];
  const float* b1    = (const float*)d_in[3];
  const float* wo    = (const float*)d_in[4];
  const float* bo    = (const float*)d_in[5];
  const float* gamma = (const float*)d_in[6];
  const float* beta  = (const float*)d_in[7];
  float* out = (float*)d_out;

  char* p = (char*)d_ws;
  unsigned short* w1t = (unsigned short*)p; p += (size_t)NE * ID * HD * 2;   // 67 MB
  unsigned short* wot = (unsigned short*)p; p += (size_t)HD * ID * 2;        // 8.4 MB
  unsigned short* xb  = (unsigned short*)p; p += (size_t)NTOK * HD * 2;      // 16.8 MB
  unsigned short* interb = (unsigned short*)p; p += (size_t)NTOK * ID * 2;   // 67 MB
  int* eidx = (int*)p; p += (size_t)NTOK * 4;
  int* perm = (int*)p; p += (size_t)NTOK * 4;
  int* ints = (int*)p;
  int* counts    = ints;        // 8
  int* cursors   = ints + 8;    // 8
  int* offs      = ints + 16;   // 9
  int* ntiles    = ints + 25;   // 1
  int* tile_e    = ints + 32;   // 72
  int* tile_base = ints + 104;  // 72
  int* tile_len  = ints + 176;  // 72

  zero_counts_kernel<<<1, 64, 0, stream>>>(counts);
  router_kernel<<<NTOK / 4, 256, 0, stream>>>(x, wr, eidx, counts, xb);
  transpose_cast_kernel<<<dim3(ID / 64, HD / 64, NE), 256, 0, stream>>>(w1, w1t, HD, ID);
  transpose_cast_kernel<<<dim3(HD / 64, ID / 64, 1), 256, 0, stream>>>(wo, wot, ID, HD);
  scan_tiles_kernel<<<1, 64, 0, stream>>>(counts, offs, ntiles, tile_e, tile_base, tile_len);
  scatter_kernel<<<NTOK / 256, 256, 0, stream>>>(eidx, offs, cursors, perm);
  ffn1_kernel<<<dim3(ID / 128, MAXTILES), 256, 0, stream>>>(
      xb, w1t, b1, perm, ntiles, tile_e, tile_base, tile_len, interb);
  ffn2_kernel<<<dim3(HD / 128, NTOK / 128), 256, 0, stream>>>(interb, wot, bo, x, out);
  ln_kernel<<<NTOK, 256, 0, stream>>>(out, gamma, beta);
}

// Round 4
// 500.959 us; speedup vs baseline: 1.2608x; 1.2196x over previous
//
#include <hip/hip_runtime.h>
#include <hip/hip_bf16.h>
#include <math.h>

#define NTOK 8192
#define HD 1024
#define ID 4096
#define NE 8
#define MAXTILES 72
#define SORTT 512

typedef __attribute__((ext_vector_type(8))) short short8;
typedef __attribute__((ext_vector_type(8))) unsigned short ushort8;
typedef __attribute__((ext_vector_type(4))) float floatx4;

__device__ __forceinline__ unsigned short f2bf(float f) {
  unsigned int u = __float_as_uint(f);
  return (unsigned short)((u + 0x7fffu + ((u >> 16) & 1u)) >> 16);
}

__device__ __forceinline__ void async_ld16(const void* g, void* l) {
  __builtin_amdgcn_global_load_lds(
      (const __attribute__((address_space(1))) unsigned int*)g,
      (__attribute__((address_space(3))) unsigned int*)l,
      16, 0, 0);
}

// ---------------- small kernels ----------------

// src: batch of [R][C] fp32, dst: batch of [C][R] bf16.
// 64x64 tile; float4 reads (16B/lane), ushort8 writes (16B/lane, 128B
// contiguous per 8-lane group). LDS padded to 65 -> <=2-way conflicts (free).
__global__ void transpose_cast_kernel(const float* __restrict__ src,
                                      unsigned short* __restrict__ dst, int R, int C) {
  size_t bo = (size_t)blockIdx.z * R * C;
  src += bo; dst += bo;
  __shared__ float t[64][65];
  int c0 = blockIdx.x * 64, r0 = blockIdx.y * 64;
  int tid = threadIdx.x;
  int rr = tid >> 4, c4 = (tid & 15) * 4;
#pragma unroll
  for (int q = 0; q < 4; q++) {
    int r = rr + q * 16;
    float4 v = *(const float4*)(src + (size_t)(r0 + r) * C + c0 + c4);
    t[r][c4] = v.x; t[r][c4 + 1] = v.y; t[r][c4 + 2] = v.z; t[r][c4 + 3] = v.w;
  }
  __syncthreads();
  int r8 = (tid & 7) * 8;
#pragma unroll
  for (int q = 0; q < 2; q++) {
    int cc = (tid >> 3) + q * 32;
    ushort8 o;
#pragma unroll
    for (int i = 0; i < 8; i++) o[i] = f2bf(t[r8 + i][cc]);
    *(ushort8*)(dst + (size_t)(c0 + cc) * R + r0 + r8) = o;
  }
}

// fp64-accumulated router logits + argmax; also emits xb = bf16(x).
// NO atomics (R3 showed 194us of contended-atomic serialization here).
__global__ void router_kernel(const float* __restrict__ x, const float* __restrict__ wr,
                              int* __restrict__ eidx, unsigned short* __restrict__ xb) {
  int wave = threadIdx.x >> 6, lane = threadIdx.x & 63;
  int n = blockIdx.x * 4 + wave;
  const float* xr = x + (size_t)n * HD;
  unsigned short* xbr = xb + (size_t)n * HD;
  double acc[NE];
#pragma unroll
  for (int e = 0; e < NE; e++) acc[e] = 0.0;
#pragma unroll
  for (int v = 0; v < 4; v++) {
    int h = (lane + v * 64) * 4;
    float4 xv = *(const float4*)(xr + h);
    ushort4 o;
    o.x = f2bf(xv.x); o.y = f2bf(xv.y); o.z = f2bf(xv.z); o.w = f2bf(xv.w);
    *(ushort4*)(xbr + h) = o;
#pragma unroll
    for (int e = 0; e < NE; e++) {
      float4 wv = *(const float4*)(wr + e * HD + h);
      acc[e] += (double)xv.x * wv.x + (double)xv.y * wv.y +
                (double)xv.z * wv.z + (double)xv.w * wv.w;
    }
  }
#pragma unroll
  for (int m = 32; m >= 1; m >>= 1) {
#pragma unroll
    for (int e = 0; e < NE; e++) acc[e] += __shfl_xor(acc[e], m, 64);
  }
  if (lane == 0) {
    int best = 0; double bv = acc[0];
#pragma unroll
    for (int e = 1; e < NE; e++) if (acc[e] > bv) { bv = acc[e]; best = e; }
    eidx[n] = best;
  }
}

// Single-block deterministic counting sort: eidx -> perm + tile table.
// 512 threads = 8 waves; wave w owns expert w's scan. Zero global atomics.
__global__ __launch_bounds__(SORTT) void sort_kernel(
    const int* __restrict__ eidx, int* __restrict__ ntiles, int* __restrict__ tile_e,
    int* __restrict__ tile_base, int* __restrict__ tile_len, int* __restrict__ perm) {
  __shared__ int h[NE][SORTT];  // 16 KB
  __shared__ int off_sh[NE];
  __shared__ int tot[NE];
  int t = threadIdx.x;
  int wave = t >> 6, lane = t & 63;
  const int base = t * (NTOK / SORTT);  // 16 tokens/thread

  // phase 1: per-thread histogram (order-preserving record of experts)
  int myexp[NTOK / SORTT];
  int loc[NE];
#pragma unroll
  for (int e = 0; e < NE; e++) loc[e] = 0;
#pragma unroll
  for (int i = 0; i < NTOK / SORTT; i++) {
    int e = eidx[base + i];
    myexp[i] = e;
    loc[e]++;
  }
#pragma unroll
  for (int e = 0; e < NE; e++) h[e][t] = loc[e];
  __syncthreads();

  // phase 2: wave `wave` does stable exclusive scan of h[wave][0..511]
  {
    int e = wave;
    int v[8], s = 0;
#pragma unroll
    for (int i = 0; i < 8; i++) { v[i] = h[e][lane * 8 + i]; s += v[i]; }
    int inc = s;
#pragma unroll
    for (int d = 1; d < 64; d <<= 1) {
      int o = __shfl_up(inc, d, 64);
      if (lane >= d) inc += o;
    }
    int exc = inc - s;
#pragma unroll
    for (int i = 0; i < 8; i++) { h[e][lane * 8 + i] = exc; exc += v[i]; }
    if (lane == 63) tot[e] = inc;
  }
  __syncthreads();

  // phase 3: expert offsets + M-tile table (serial, tiny)
  if (t == 0) {
    int s = 0, tt = 0;
    for (int e = 0; e < NE; e++) {
      off_sh[e] = s;
      int c = tot[e];
      for (int b = 0; b < c; b += 128) {
        tile_e[tt] = e;
        tile_base[tt] = s + b;
        tile_len[tt] = (c - b < 128) ? (c - b) : 128;
        tt++;
      }
      s += c;
    }
    *ntiles = tt;
  }
  __syncthreads();

  // phase 4: stable scatter of token ids
  int cur[NE];
#pragma unroll
  for (int e = 0; e < NE; e++) cur[e] = off_sh[e] + h[e][t];
#pragma unroll
  for (int i = 0; i < NTOK / SORTT; i++) {
    int e = myexp[i];
    perm[cur[e]++] = base + i;
  }
}

// ---------------- GEMM kernels ----------------
// 128x128 tile, BK=64, 4 waves (2x2), 4x4 MFMA frags/wave, 16x16x32 bf16.
// LDS layout: [row][64] bf16, 16B chunks XOR-swizzled by (row&7) so both
// global_load_lds staging (lane*16 contiguous) and ds_read_b128 frag reads
// are conflict-free (SQ_LDS_BANK_CONFLICT==0 measured R1-R3).

__global__ __launch_bounds__(256, 2) void ffn1_kernel(
    const unsigned short* __restrict__ xb, const unsigned short* __restrict__ w1t,
    const float* __restrict__ b1, const int* __restrict__ perm,
    const int* __restrict__ ntiles, const int* __restrict__ tile_e,
    const int* __restrict__ tile_base, const int* __restrict__ tile_len,
    unsigned short* __restrict__ interb) {
  int t = blockIdx.y;
  if (t >= *ntiles) return;
  int e = tile_e[t], base = tile_base[t], len = tile_len[t];
  int nb = blockIdx.x * 128;

  __shared__ unsigned short lA[128 * 64];
  __shared__ unsigned short lB[128 * 64];

  int tid = threadIdx.x;
  int wave = tid >> 6, lane = tid & 63;
  int lr = lane >> 3;              // row-within-8-row-chunk
  int chunk = (lane & 7) ^ lr;     // swizzled 16B chunk selector

  const unsigned short* gA[4];
  const unsigned short* gB[4];
#pragma unroll
  for (int q = 0; q < 4; q++) {
    int c = wave * 4 + q;
    int tr = c * 8 + lr;
    int token = perm[base + (tr < len ? tr : len - 1)];  // clamp tail (stores masked)
    gA[q] = xb + (size_t)token * HD + chunk * 8;
    int nr = nb + c * 8 + lr;
    gB[q] = w1t + ((size_t)e * ID + nr) * HD + chunk * 8;
  }

  floatx4 acc[4][4];
#pragma unroll
  for (int i = 0; i < 4; i++)
#pragma unroll
    for (int j = 0; j < 4; j++) acc[i][j] = (floatx4){0.f, 0.f, 0.f, 0.f};

  int wm = (wave >> 1) * 64, wn = (wave & 1) * 64;
  int c15 = lane & 15, q4 = lane >> 4;

  for (int ko = 0; ko < HD / 64; ko++) {
#pragma unroll
    for (int q = 0; q < 4; q++) {
      int c = wave * 4 + q;
      async_ld16(gA[q] + ko * 64, &lA[c * 512]);
      async_ld16(gB[q] + ko * 64, &lB[c * 512]);
    }
    __syncthreads();
#pragma unroll
    for (int kk = 0; kk < 2; kk++) {
      short8 af[4], bfr[4];
#pragma unroll
      for (int i = 0; i < 4; i++) {
        int m = wm + i * 16 + c15;
        int sa = (kk * 4 + q4) ^ (m & 7);
        af[i] = *(const short8*)&lA[m * 64 + sa * 8];
        int n = wn + i * 16 + c15;
        int sb = (kk * 4 + q4) ^ (n & 7);
        bfr[i] = *(const short8*)&lB[n * 64 + sb * 8];
      }
#pragma unroll
      for (int i = 0; i < 4; i++)
#pragma unroll
        for (int j = 0; j < 4; j++)
          acc[i][j] = __builtin_amdgcn_mfma_f32_16x16x32_bf16(af[i], bfr[j], acc[i][j], 0, 0, 0);
    }
    __syncthreads();
  }

#pragma unroll
  for (int i = 0; i < 4; i++) {
#pragma unroll
    for (int r = 0; r < 4; r++) {
      int tr = wm + i * 16 + q4 * 4 + r;
      if (tr >= len) continue;
      int token = perm[base + tr];
#pragma unroll
      for (int j = 0; j < 4; j++) {
        int col = nb + wn + j * 16 + c15;
        float v = acc[i][j][r] + b1[e * ID + col];
        v = 0.5f * v * (1.0f + erff(v * 0.70710678118654752f));  // exact GELU
        interb[(size_t)token * ID + col] = f2bf(v);
      }
    }
  }
}

// full-K ffn2, fused bias + residual; writes pre-LN y (fp32) to d_out.
__global__ __launch_bounds__(256, 2) void ffn2_kernel(
    const unsigned short* __restrict__ interb, const unsigned short* __restrict__ wot,
    const float* __restrict__ bo, const float* __restrict__ x, float* __restrict__ y) {
  int tm = blockIdx.y;
  int nb = blockIdx.x * 128;

  __shared__ unsigned short lA[128 * 64];
  __shared__ unsigned short lB[128 * 64];

  int tid = threadIdx.x;
  int wave = tid >> 6, lane = tid & 63;
  int lr = lane >> 3;
  int chunk = (lane & 7) ^ lr;

  const unsigned short* gA[4];
  const unsigned short* gB[4];
#pragma unroll
  for (int q = 0; q < 4; q++) {
    int c = wave * 4 + q;
    int row = tm * 128 + c * 8 + lr;
    gA[q] = interb + (size_t)row * ID + chunk * 8;
    int nr = nb + c * 8 + lr;
    gB[q] = wot + (size_t)nr * ID + chunk * 8;
  }

  floatx4 acc[4][4];
#pragma unroll
  for (int i = 0; i < 4; i++)
#pragma unroll
    for (int j = 0; j < 4; j++) acc[i][j] = (floatx4){0.f, 0.f, 0.f, 0.f};

  int wm = (wave >> 1) * 64, wn = (wave & 1) * 64;
  int c15 = lane & 15, q4 = lane >> 4;

  for (int ko = 0; ko < ID / 64; ko++) {
#pragma unroll
    for (int q = 0; q < 4; q++) {
      int c = wave * 4 + q;
      async_ld16(gA[q] + ko * 64, &lA[c * 512]);
      async_ld16(gB[q] + ko * 64, &lB[c * 512]);
    }
    __syncthreads();
#pragma unroll
    for (int kk = 0; kk < 2; kk++) {
      short8 af[4], bfr[4];
#pragma unroll
      for (int i = 0; i < 4; i++) {
        int m = wm + i * 16 + c15;
        int sa = (kk * 4 + q4) ^ (m & 7);
        af[i] = *(const short8*)&lA[m * 64 + sa * 8];
        int n = wn + i * 16 + c15;
        int sb = (kk * 4 + q4) ^ (n & 7);
        bfr[i] = *(const short8*)&lB[n * 64 + sb * 8];
      }
#pragma unroll
      for (int i = 0; i < 4; i++)
#pragma unroll
        for (int j = 0; j < 4; j++)
          acc[i][j] = __builtin_amdgcn_mfma_f32_16x16x32_bf16(af[i], bfr[j], acc[i][j], 0, 0, 0);
    }
    __syncthreads();
  }

#pragma unroll
  for (int i = 0; i < 4; i++) {
#pragma unroll
    for (int r = 0; r < 4; r++) {
      int row = tm * 128 + wm + i * 16 + q4 * 4 + r;
#pragma unroll
      for (int j = 0; j < 4; j++) {
        int col = nb + wn + j * 16 + c15;
        float v = acc[i][j][r] + bo[col] + x[(size_t)row * HD + col];
        y[(size_t)row * HD + col] = v;  // pre-LN y staged in d_out
      }
    }
  }
}

__global__ void ln_kernel(float* __restrict__ y, const float* __restrict__ gamma,
                          const float* __restrict__ beta) {
  int row = blockIdx.x, t = threadIdx.x;
  int lane = t & 63, wave = t >> 6;
  float* yr = y + (size_t)row * HD;
  float4 v = *(const float4*)(yr + t * 4);
  float s = v.x + v.y + v.z + v.w;
  float ss = v.x * v.x + v.y * v.y + v.z * v.z + v.w * v.w;
#pragma unroll
  for (int m = 32; m >= 1; m >>= 1) {
    s += __shfl_xor(s, m, 64);
    ss += __shfl_xor(ss, m, 64);
  }
  __shared__ float sred[4], ssred[4];
  if (lane == 0) { sred[wave] = s; ssred[wave] = ss; }
  __syncthreads();
  s = sred[0] + sred[1] + sred[2] + sred[3];
  ss = ssred[0] + ssred[1] + ssred[2] + ssred[3];
  float mu = s * (1.0f / HD);
  float var = ss * (1.0f / HD) - mu * mu;
  float rs = rsqrtf(var + 1e-12f);
  float4 g = *(const float4*)(gamma + t * 4);
  float4 b = *(const float4*)(beta + t * 4);
  float4 o;
  o.x = (v.x - mu) * rs * g.x + b.x;
  o.y = (v.y - mu) * rs * g.y + b.y;
  o.z = (v.z - mu) * rs * g.z + b.z;
  o.w = (v.w - mu) * rs * g.w + b.w;
  *(float4*)(yr + t * 4) = o;
}

// ---------------- host launcher ----------------

extern "C" void kernel_launch(void* const* d_in, const int* in_sizes, int n_in,
                              void* d_out, int out_size, void* d_ws, size_t ws_size,
                              hipStream_t stream) {
  const float* x     = (const float*)d_in[0];
  const float* wr    = (const float*)d_in[1];
  const float* w1    = (const float*)d_in[2];
  const float* b1    = (const float*)d_in[3];
  const float* wo    = (const float*)d_in[4];
  const float* bo    = (const float*)d_in[5];
  const float* gamma = (const float*)d_in[6];
  const float* beta  = (const float*)d_in[7];
  float* out = (float*)d_out;

  char* p = (char*)d_ws;
  unsigned short* w1t = (unsigned short*)p; p += (size_t)NE * ID * HD * 2;   // 67 MB
  unsigned short* wot = (unsigned short*)p; p += (size_t)HD * ID * 2;        // 8.4 MB
  unsigned short* xb  = (unsigned short*)p; p += (size_t)NTOK * HD * 2;      // 16.8 MB
  unsigned short* interb = (unsigned short*)p; p += (size_t)NTOK * ID * 2;   // 67 MB
  int* eidx = (int*)p; p += (size_t)NTOK * 4;
  int* perm = (int*)p; p += (size_t)NTOK * 4;
  int* ints = (int*)p;
  int* ntiles    = ints;        // 1
  int* tile_e    = ints + 8;    // 72
  int* tile_base = ints + 80;   // 72
  int* tile_len  = ints + 152;  // 72

  router_kernel<<<NTOK / 4, 256, 0, stream>>>(x, wr, eidx, xb);
  transpose_cast_kernel<<<dim3(ID / 64, HD / 64, NE), 256, 0, stream>>>(w1, w1t, HD, ID);
  transpose_cast_kernel<<<dim3(HD / 64, ID / 64, 1), 256, 0, stream>>>(wo, wot, ID, HD);
  sort_kernel<<<1, SORTT, 0, stream>>>(eidx, ntiles, tile_e, tile_base, tile_len, perm);
  ffn1_kernel<<<dim3(ID / 128, MAXTILES), 256, 0, stream>>>(
      xb, w1t, b1, perm, ntiles, tile_e, tile_base, tile_len, interb);
  ffn2_kernel<<<dim3(HD / 128, NTOK / 128), 256, 0, stream>>>(interb, wot, bo, x, out);
  ln_kernel<<<NTOK, 256, 0, stream>>>(out, gamma, beta);
}

// Round 5
// 496.357 us; speedup vs baseline: 1.2725x; 1.0093x over previous
//
#include <hip/hip_runtime.h>
#include <hip/hip_bf16.h>
#include <math.h>

#define NTOK 8192
#define HD 1024
#define ID 4096
#define NE 8
#define MAXTILES 72
#define SORTT 512
#define TPT (NTOK / SORTT)  // 16 tokens per sort thread

typedef __attribute__((ext_vector_type(8))) short short8;
typedef __attribute__((ext_vector_type(8))) unsigned short ushort8;
typedef __attribute__((ext_vector_type(4))) float floatx4;

__device__ __forceinline__ unsigned short f2bf(float f) {
  unsigned int u = __float_as_uint(f);
  return (unsigned short)((u + 0x7fffu + ((u >> 16) & 1u)) >> 16);
}

__device__ __forceinline__ void async_ld16(const void* g, void* l) {
  __builtin_amdgcn_global_load_lds(
      (const __attribute__((address_space(1))) unsigned int*)g,
      (__attribute__((address_space(3))) unsigned int*)l,
      16, 0, 0);
}

// ---------------- small kernels ----------------

// src: batch of [R][C] fp32, dst: batch of [C][R] bf16.
// 64x64 tile; float4 reads (16B/lane), ushort8 writes (16B/lane, 128B
// contiguous per 8-lane group). LDS padded to 65 -> <=2-way conflicts (free).
__global__ void transpose_cast_kernel(const float* __restrict__ src,
                                      unsigned short* __restrict__ dst, int R, int C) {
  size_t bo = (size_t)blockIdx.z * R * C;
  src += bo; dst += bo;
  __shared__ float t[64][65];
  int c0 = blockIdx.x * 64, r0 = blockIdx.y * 64;
  int tid = threadIdx.x;
  int rr = tid >> 4, c4 = (tid & 15) * 4;
#pragma unroll
  for (int q = 0; q < 4; q++) {
    int r = rr + q * 16;
    float4 v = *(const float4*)(src + (size_t)(r0 + r) * C + c0 + c4);
    t[r][c4] = v.x; t[r][c4 + 1] = v.y; t[r][c4 + 2] = v.z; t[r][c4 + 3] = v.w;
  }
  __syncthreads();
  int r8 = (tid & 7) * 8;
#pragma unroll
  for (int q = 0; q < 2; q++) {
    int cc = (tid >> 3) + q * 32;
    ushort8 o;
#pragma unroll
    for (int i = 0; i < 8; i++) o[i] = f2bf(t[r8 + i][cc]);
    *(ushort8*)(dst + (size_t)(c0 + cc) * R + r0 + r8) = o;
  }
}

// fp64-accumulated router logits + argmax; also emits xb = bf16(x). No atomics.
__global__ void router_kernel(const float* __restrict__ x, const float* __restrict__ wr,
                              int* __restrict__ eidx, unsigned short* __restrict__ xb) {
  int wave = threadIdx.x >> 6, lane = threadIdx.x & 63;
  int n = blockIdx.x * 4 + wave;
  const float* xr = x + (size_t)n * HD;
  unsigned short* xbr = xb + (size_t)n * HD;
  double acc[NE];
#pragma unroll
  for (int e = 0; e < NE; e++) acc[e] = 0.0;
#pragma unroll
  for (int v = 0; v < 4; v++) {
    int h = (lane + v * 64) * 4;
    float4 xv = *(const float4*)(xr + h);
    ushort4 o;
    o.x = f2bf(xv.x); o.y = f2bf(xv.y); o.z = f2bf(xv.z); o.w = f2bf(xv.w);
    *(ushort4*)(xbr + h) = o;
#pragma unroll
    for (int e = 0; e < NE; e++) {
      float4 wv = *(const float4*)(wr + e * HD + h);
      acc[e] += (double)xv.x * wv.x + (double)xv.y * wv.y +
                (double)xv.z * wv.z + (double)xv.w * wv.w;
    }
  }
#pragma unroll
  for (int m = 32; m >= 1; m >>= 1) {
#pragma unroll
    for (int e = 0; e < NE; e++) acc[e] += __shfl_xor(acc[e], m, 64);
  }
  if (lane == 0) {
    int best = 0; double bv = acc[0];
#pragma unroll
    for (int e = 1; e < NE; e++) if (acc[e] > bv) { bv = acc[e]; best = e; }
    eidx[n] = best;
  }
}

// Single-block deterministic counting sort: eidx -> perm + tile table.
// SCRATCH-FREE: no dynamically-indexed private arrays (R4's version spilled
// loc[e]/cur[e] to scratch -> ~100us of single-CU serialization). Counters
// live in 8 distinct VGPRs via statically-unrolled compare-select.
__global__ __launch_bounds__(SORTT) void sort_kernel(
    const int* __restrict__ eidx, int* __restrict__ ntiles, int* __restrict__ tile_e,
    int* __restrict__ tile_base, int* __restrict__ tile_len, int* __restrict__ perm) {
  __shared__ int h[NE][SORTT];  // 16 KB
  __shared__ int off_sh[NE];
  __shared__ int tot[NE];
  int t = threadIdx.x;
  int wave = t >> 6, lane = t & 63;
  const int base = t * TPT;

  // phase 1: load 16 expert ids (int4 x4), histogram in static VGPR counters
  int4 e0 = *(const int4*)(eidx + base);
  int4 e1 = *(const int4*)(eidx + base + 4);
  int4 e2 = *(const int4*)(eidx + base + 8);
  int4 e3 = *(const int4*)(eidx + base + 12);
  int ex[TPT] = {e0.x, e0.y, e0.z, e0.w, e1.x, e1.y, e1.z, e1.w,
                 e2.x, e2.y, e2.z, e2.w, e3.x, e3.y, e3.z, e3.w};
  int cnt0 = 0, cnt1 = 0, cnt2 = 0, cnt3 = 0, cnt4 = 0, cnt5 = 0, cnt6 = 0, cnt7 = 0;
#pragma unroll
  for (int i = 0; i < TPT; i++) {
    int e = ex[i];
    cnt0 += (e == 0); cnt1 += (e == 1); cnt2 += (e == 2); cnt3 += (e == 3);
    cnt4 += (e == 4); cnt5 += (e == 5); cnt6 += (e == 6); cnt7 += (e == 7);
  }
  h[0][t] = cnt0; h[1][t] = cnt1; h[2][t] = cnt2; h[3][t] = cnt3;
  h[4][t] = cnt4; h[5][t] = cnt5; h[6][t] = cnt6; h[7][t] = cnt7;
  __syncthreads();

  // phase 2: wave `wave` does stable exclusive scan of h[wave][0..511]
  {
    int e = wave;
    int v[8], s = 0;
#pragma unroll
    for (int i = 0; i < 8; i++) { v[i] = h[e][lane * 8 + i]; s += v[i]; }
    int inc = s;
#pragma unroll
    for (int d = 1; d < 64; d <<= 1) {
      int o = __shfl_up(inc, d, 64);
      if (lane >= d) inc += o;
    }
    int exc = inc - s;
#pragma unroll
    for (int i = 0; i < 8; i++) { h[e][lane * 8 + i] = exc; exc += v[i]; }
    if (lane == 63) tot[e] = inc;
  }
  __syncthreads();

  // phase 3: expert offsets + M-tile table (serial, tiny)
  if (t == 0) {
    int s = 0, tt = 0;
    for (int e = 0; e < NE; e++) {
      off_sh[e] = s;
      int c = tot[e];
      for (int b = 0; b < c; b += 128) {
        tile_e[tt] = e;
        tile_base[tt] = s + b;
        tile_len[tt] = (c - b < 128) ? (c - b) : 128;
        tt++;
      }
      s += c;
    }
    *ntiles = tt;
  }
  __syncthreads();

  // phase 4: stable scatter; cursors in static VGPRs (no scratch)
  int c0c = off_sh[0] + h[0][t], c1c = off_sh[1] + h[1][t];
  int c2c = off_sh[2] + h[2][t], c3c = off_sh[3] + h[3][t];
  int c4c = off_sh[4] + h[4][t], c5c = off_sh[5] + h[5][t];
  int c6c = off_sh[6] + h[6][t], c7c = off_sh[7] + h[7][t];
#pragma unroll
  for (int i = 0; i < TPT; i++) {
    int e = ex[i];
    int pos = c0c;
    pos = (e == 1) ? c1c : pos; pos = (e == 2) ? c2c : pos;
    pos = (e == 3) ? c3c : pos; pos = (e == 4) ? c4c : pos;
    pos = (e == 5) ? c5c : pos; pos = (e == 6) ? c6c : pos;
    pos = (e == 7) ? c7c : pos;
    perm[pos] = base + i;
    c0c += (e == 0); c1c += (e == 1); c2c += (e == 2); c3c += (e == 3);
    c4c += (e == 4); c5c += (e == 5); c6c += (e == 6); c7c += (e == 7);
  }
}

// ---------------- GEMM kernels ----------------
// 128x128 tile, BK=64, 4 waves (2x2), 4x4 MFMA frags/wave, 16x16x32 bf16.
// LDS layout: [row][64] bf16, 16B chunks XOR-swizzled by (row&7) so both
// global_load_lds staging (lane*16 contiguous) and ds_read_b128 frag reads
// are conflict-free (SQ_LDS_BANK_CONFLICT==0 measured R1-R4).

__global__ __launch_bounds__(256, 2) void ffn1_kernel(
    const unsigned short* __restrict__ xb, const unsigned short* __restrict__ w1t,
    const float* __restrict__ b1, const int* __restrict__ perm,
    const int* __restrict__ ntiles, const int* __restrict__ tile_e,
    const int* __restrict__ tile_base, const int* __restrict__ tile_len,
    unsigned short* __restrict__ interb) {
  int t = blockIdx.y;
  if (t >= *ntiles) return;
  int e = tile_e[t], base = tile_base[t], len = tile_len[t];
  int nb = blockIdx.x * 128;

  __shared__ unsigned short lA[128 * 64];
  __shared__ unsigned short lB[128 * 64];

  int tid = threadIdx.x;
  int wave = tid >> 6, lane = tid & 63;
  int lr = lane >> 3;              // row-within-8-row-chunk
  int chunk = (lane & 7) ^ lr;     // swizzled 16B chunk selector

  const unsigned short* gA[4];
  const unsigned short* gB[4];
#pragma unroll
  for (int q = 0; q < 4; q++) {
    int c = wave * 4 + q;
    int tr = c * 8 + lr;
    int token = perm[base + (tr < len ? tr : len - 1)];  // clamp tail (stores masked)
    gA[q] = xb + (size_t)token * HD + chunk * 8;
    int nr = nb + c * 8 + lr;
    gB[q] = w1t + ((size_t)e * ID + nr) * HD + chunk * 8;
  }

  floatx4 acc[4][4];
#pragma unroll
  for (int i = 0; i < 4; i++)
#pragma unroll
    for (int j = 0; j < 4; j++) acc[i][j] = (floatx4){0.f, 0.f, 0.f, 0.f};

  int wm = (wave >> 1) * 64, wn = (wave & 1) * 64;
  int c15 = lane & 15, q4 = lane >> 4;

  for (int ko = 0; ko < HD / 64; ko++) {
#pragma unroll
    for (int q = 0; q < 4; q++) {
      int c = wave * 4 + q;
      async_ld16(gA[q] + ko * 64, &lA[c * 512]);
      async_ld16(gB[q] + ko * 64, &lB[c * 512]);
    }
    __syncthreads();
#pragma unroll
    for (int kk = 0; kk < 2; kk++) {
      short8 af[4], bfr[4];
#pragma unroll
      for (int i = 0; i < 4; i++) {
        int m = wm + i * 16 + c15;
        int sa = (kk * 4 + q4) ^ (m & 7);
        af[i] = *(const short8*)&lA[m * 64 + sa * 8];
        int n = wn + i * 16 + c15;
        int sb = (kk * 4 + q4) ^ (n & 7);
        bfr[i] = *(const short8*)&lB[n * 64 + sb * 8];
      }
#pragma unroll
      for (int i = 0; i < 4; i++)
#pragma unroll
        for (int j = 0; j < 4; j++)
          acc[i][j] = __builtin_amdgcn_mfma_f32_16x16x32_bf16(af[i], bfr[j], acc[i][j], 0, 0, 0);
    }
    __syncthreads();
  }

#pragma unroll
  for (int i = 0; i < 4; i++) {
#pragma unroll
    for (int r = 0; r < 4; r++) {
      int tr = wm + i * 16 + q4 * 4 + r;
      if (tr >= len) continue;
      int token = perm[base + tr];
#pragma unroll
      for (int j = 0; j < 4; j++) {
        int col = nb + wn + j * 16 + c15;
        float v = acc[i][j][r] + b1[e * ID + col];
        v = 0.5f * v * (1.0f + erff(v * 0.70710678118654752f));  // exact GELU
        interb[(size_t)token * ID + col] = f2bf(v);
      }
    }
  }
}

// full-K ffn2, fused bias + residual; writes pre-LN y (fp32) to d_out.
__global__ __launch_bounds__(256, 2) void ffn2_kernel(
    const unsigned short* __restrict__ interb, const unsigned short* __restrict__ wot,
    const float* __restrict__ bo, const float* __restrict__ x, float* __restrict__ y) {
  int tm = blockIdx.y;
  int nb = blockIdx.x * 128;

  __shared__ unsigned short lA[128 * 64];
  __shared__ unsigned short lB[128 * 64];

  int tid = threadIdx.x;
  int wave = tid >> 6, lane = tid & 63;
  int lr = lane >> 3;
  int chunk = (lane & 7) ^ lr;

  const unsigned short* gA[4];
  const unsigned short* gB[4];
#pragma unroll
  for (int q = 0; q < 4; q++) {
    int c = wave * 4 + q;
    int row = tm * 128 + c * 8 + lr;
    gA[q] = interb + (size_t)row * ID + chunk * 8;
    int nr = nb + c * 8 + lr;
    gB[q] = wot + (size_t)nr * ID + chunk * 8;
  }

  floatx4 acc[4][4];
#pragma unroll
  for (int i = 0; i < 4; i++)
#pragma unroll
    for (int j = 0; j < 4; j++) acc[i][j] = (floatx4){0.f, 0.f, 0.f, 0.f};

  int wm = (wave >> 1) * 64, wn = (wave & 1) * 64;
  int c15 = lane & 15, q4 = lane >> 4;

  for (int ko = 0; ko < ID / 64; ko++) {
#pragma unroll
    for (int q = 0; q < 4; q++) {
      int c = wave * 4 + q;
      async_ld16(gA[q] + ko * 64, &lA[c * 512]);
      async_ld16(gB[q] + ko * 64, &lB[c * 512]);
    }
    __syncthreads();
#pragma unroll
    for (int kk = 0; kk < 2; kk++) {
      short8 af[4], bfr[4];
#pragma unroll
      for (int i = 0; i < 4; i++) {
        int m = wm + i * 16 + c15;
        int sa = (kk * 4 + q4) ^ (m & 7);
        af[i] = *(const short8*)&lA[m * 64 + sa * 8];
        int n = wn + i * 16 + c15;
        int sb = (kk * 4 + q4) ^ (n & 7);
        bfr[i] = *(const short8*)&lB[n * 64 + sb * 8];
      }
#pragma unroll
      for (int i = 0; i < 4; i++)
#pragma unroll
        for (int j = 0; j < 4; j++)
          acc[i][j] = __builtin_amdgcn_mfma_f32_16x16x32_bf16(af[i], bfr[j], acc[i][j], 0, 0, 0);
    }
    __syncthreads();
  }

#pragma unroll
  for (int i = 0; i < 4; i++) {
#pragma unroll
    for (int r = 0; r < 4; r++) {
      int row = tm * 128 + wm + i * 16 + q4 * 4 + r;
#pragma unroll
      for (int j = 0; j < 4; j++) {
        int col = nb + wn + j * 16 + c15;
        float v = acc[i][j][r] + bo[col] + x[(size_t)row * HD + col];
        y[(size_t)row * HD + col] = v;  // pre-LN y staged in d_out
      }
    }
  }
}

__global__ void ln_kernel(float* __restrict__ y, const float* __restrict__ gamma,
                          const float* __restrict__ beta) {
  int row = blockIdx.x, t = threadIdx.x;
  int lane = t & 63, wave = t >> 6;
  float* yr = y + (size_t)row * HD;
  float4 v = *(const float4*)(yr + t * 4);
  float s = v.x + v.y + v.z + v.w;
  float ss = v.x * v.x + v.y * v.y + v.z * v.z + v.w * v.w;
#pragma unroll
  for (int m = 32; m >= 1; m >>= 1) {
    s += __shfl_xor(s, m, 64);
    ss += __shfl_xor(ss, m, 64);
  }
  __shared__ float sred[4], ssred[4];
  if (lane == 0) { sred[wave] = s; ssred[wave] = ss; }
  __syncthreads();
  s = sred[0] + sred[1] + sred[2] + sred[3];
  ss = ssred[0] + ssred[1] + ssred[2] + ssred[3];
  float mu = s * (1.0f / HD);
  float var = ss * (1.0f / HD) - mu * mu;
  float rs = rsqrtf(var + 1e-12f);
  float4 g = *(const float4*)(gamma + t * 4);
  float4 b = *(const float4*)(beta + t * 4);
  float4 o;
  o.x = (v.x - mu) * rs * g.x + b.x;
  o.y = (v.y - mu) * rs * g.y + b.y;
  o.z = (v.z - mu) * rs * g.z + b.z;
  o.w = (v.w - mu) * rs * g.w + b.w;
  *(float4*)(yr + t * 4) = o;
}

// ---------------- host launcher ----------------

extern "C" void kernel_launch(void* const* d_in, const int* in_sizes, int n_in,
                              void* d_out, int out_size, void* d_ws, size_t ws_size,
                              hipStream_t stream) {
  const float* x     = (const float*)d_in[0];
  const float* wr    = (const float*)d_in[1];
  const float* w1    = (const float*)d_in[2];
  const float* b1    = (const float*)d_in[3];
  const float* wo    = (const float*)d_in[4];
  const float* bo    = (const float*)d_in[5];
  const float* gamma = (const float*)d_in[6];
  const float* beta  = (const float*)d_in[7];
  float* out = (float*)d_out;

  char* p = (char*)d_ws;
  unsigned short* w1t = (unsigned short*)p; p += (size_t)NE * ID * HD * 2;   // 67 MB
  unsigned short* wot = (unsigned short*)p; p += (size_t)HD * ID * 2;        // 8.4 MB
  unsigned short* xb  = (unsigned short*)p; p += (size_t)NTOK * HD * 2;      // 16.8 MB
  unsigned short* interb = (unsigned short*)p; p += (size_t)NTOK * ID * 2;   // 67 MB
  int* eidx = (int*)p; p += (size_t)NTOK * 4;
  int* perm = (int*)p; p += (size_t)NTOK * 4;
  int* ints = (int*)p;
  int* ntiles    = ints;        // 1
  int* tile_e    = ints + 8;    // 72
  int* tile_base = ints + 80;   // 72
  int* tile_len  = ints + 152;  // 72

  router_kernel<<<NTOK / 4, 256, 0, stream>>>(x, wr, eidx, xb);
  transpose_cast_kernel<<<dim3(ID / 64, HD / 64, NE), 256, 0, stream>>>(w1, w1t, HD, ID);
  transpose_cast_kernel<<<dim3(HD / 64, ID / 64, 1), 256, 0, stream>>>(wo, wot, ID, HD);
  sort_kernel<<<1, SORTT, 0, stream>>>(eidx, ntiles, tile_e, tile_base, tile_len, perm);
  ffn1_kernel<<<dim3(ID / 128, MAXTILES), 256, 0, stream>>>(
      xb, w1t, b1, perm, ntiles, tile_e, tile_base, tile_len, interb);
  ffn2_kernel<<<dim3(HD / 128, NTOK / 128), 256, 0, stream>>>(interb, wot, bo, x, out);
  ln_kernel<<<NTOK, 256, 0, stream>>>(out, gamma, beta);
}